// Round 7
// baseline (187.172 us; speedup 1.0000x reference)
//
#include <hip/hip_runtime.h>
#include <hip/hip_bf16.h>

// GAT encoder: B=16, N=768, IN=16, HID=64, HEADS=8, EMB=128, 2 GAT layers.
// Round 7: (1) s1/s2 via extra MFMA with precomputed u=W·a fragment columns
// (kills 64-shfl epilogues in k_wh1m/k_wh2); (2) ds_write_b64-packed transpose
// stores; (3) k_attn 2 K-tiles per barrier phase + float4 qv loads.
//
// ws: h0A us[786432] | Whf us[6291456] | s1 f[98304] | s2 f[98304]
//     | hpA us[6291456] | W1f us[262144] | pwf us[65536] | W0f us[32768]
//     | u01f us[65536] | u00f us[8192]

#define B_ 16
#define N_ 768
#define IN_DIM_ 16
#define HID_ 64
#define EMB_ 128
#define NH_ 8
#define F1_ (NH_ * HID_) // 512
#define LOG2E_ 1.4426950408889634f

typedef __attribute__((ext_vector_type(4))) float f32x4;
typedef __attribute__((ext_vector_type(8))) short bf16x8;
typedef __attribute__((ext_vector_type(4))) short bf16x4;

typedef __attribute__((address_space(1))) const unsigned int gu32;
typedef __attribute__((address_space(3))) unsigned int lu32;

static __device__ __forceinline__ void gload_lds16(const void* g, void* l) {
    // async global->LDS, 16B per lane; LDS dest = wave-uniform base + lane*16
    __builtin_amdgcn_global_load_lds((gu32*)g, (lu32*)l, 16, 0, 0);
}

static __device__ __forceinline__ short f2bf(float x) {
    __hip_bfloat16 b = __float2bfloat16(x);
    return *reinterpret_cast<short*>(&b);
}

// ---- prep: h0A A-fragments, W1f/pwf/W0f B-fragments, u01f/u00f (u = W·a) ----
__global__ __launch_bounds__(256) void k_prep(const float* __restrict__ x,
                                              const float* __restrict__ ipw,
                                              const float* __restrict__ ipb,
                                              const float* __restrict__ w1,
                                              const float* __restrict__ pw,
                                              const float* __restrict__ w0,
                                              const float* __restrict__ a1g,
                                              const float* __restrict__ a0g,
                                              ushort* __restrict__ h0A,
                                              ushort* __restrict__ W1f,
                                              ushort* __restrict__ pwf,
                                              ushort* __restrict__ W0f,
                                              ushort* __restrict__ u01f,
                                              ushort* __restrict__ u00f) {
    if (blockIdx.x < 384) {
        const int t = blockIdx.x * 256 + threadIdx.x;  // < 98304
        const int lane = t & 63;
        const int kt = (t >> 6) & 1;
        const int rtg = t >> 7;
        const int row = rtg * 16 + (lane & 15);
        const int k0 = kt * 32 + (lane >> 4) * 8;
        const float* xr = x + row * IN_DIM_;
        float xv[IN_DIM_];
#pragma unroll
        for (int f = 0; f < IN_DIM_; ++f) xv[f] = xr[f];
        bf16x8 v;
#pragma unroll
        for (int j = 0; j < 8; ++j) {
            float acc = ipb[k0 + j];
#pragma unroll
            for (int f = 0; f < IN_DIM_; ++f) acc = fmaf(xv[f], ipw[f * HID_ + k0 + j], acc);
            v[j] = f2bf(acc);
        }
        *(bf16x8*)&h0A[t * 8] = v;
        return;
    }
    int t = (blockIdx.x - 384) * 256 + threadIdx.x;  // < 54272
    if (t < 32768) {
        // W1f[h][kt16][nt4][lane][8] = w1[h][kt*32+(l>>4)*8+j][nt*16+(l&15)]
        int lane = t & 63, nt = (t >> 6) & 3, kt = (t >> 8) & 15, h = t >> 12;
        int k0 = kt * 32 + (lane >> 4) * 8;
        int col = nt * 16 + (lane & 15);
        const float* src = w1 + (h * 512 + k0) * 64 + col;
        bf16x8 v;
#pragma unroll
        for (int j = 0; j < 8; ++j) v[j] = f2bf(src[j * 64]);
        *(bf16x8*)&W1f[t * 8] = v;
    } else if (t < 40960) {
        int u = t - 32768;  // < 8192
        int lane = u & 63, nt = (u >> 6) & 7, kt = u >> 9;
        int k0 = kt * 32 + (lane >> 4) * 8;
        int col = nt * 16 + (lane & 15);
        const float* src = pw + k0 * 128 + col;
        bf16x8 v;
#pragma unroll
        for (int j = 0; j < 8; ++j) v[j] = f2bf(src[j * 128]);
        *(bf16x8*)&pwf[u * 8] = v;
    } else if (t < 45056) {
        int u = t - 40960;  // < 4096
        int lane = u & 63, nt = (u >> 6) & 3, kt = (u >> 8) & 1, h = u >> 9;
        int k0 = kt * 32 + (lane >> 4) * 8;
        int col = nt * 16 + (lane & 15);
        const float* src = w0 + (h * 64 + k0) * 64 + col;
        bf16x8 v;
#pragma unroll
        for (int j = 0; j < 8; ++j) v[j] = f2bf(src[j * 64]);
        *(bf16x8*)&W0f[u * 8] = v;
    } else if (t < 53248) {
        // u01f[h][kt16][lane][8]: col0=u1, col1=u2, else 0; u = w1[h]·a1/a2
        int u = t - 45056;  // < 8192
        int lane = u & 63, kt = (u >> 6) & 15, h = u >> 10;
        int ll = lane & 15, lg = lane >> 4;
        bf16x8 v = {0, 0, 0, 0, 0, 0, 0, 0};
        if (ll < 2) {
            int k0 = kt * 32 + lg * 8;
            const float* av = a1g + h * 128 + (ll ? 64 : 0);
            float acc[8] = {0.f, 0.f, 0.f, 0.f, 0.f, 0.f, 0.f, 0.f};
            for (int o = 0; o < 64; ++o) {
                float a = av[o];
#pragma unroll
                for (int j = 0; j < 8; ++j)
                    acc[j] = fmaf(w1[(h * 512 + k0 + j) * 64 + o], a, acc[j]);
            }
#pragma unroll
            for (int j = 0; j < 8; ++j) v[j] = f2bf(acc[j]);
        }
        *(bf16x8*)&u01f[u * 8] = v;
    } else {
        // u00f[h][kt2][lane][8]: col0=u1, col1=u2 from w0[h]·a0
        int u = t - 53248;  // < 1024
        int lane = u & 63, kt = (u >> 6) & 1, h = u >> 7;
        int ll = lane & 15, lg = lane >> 4;
        bf16x8 v = {0, 0, 0, 0, 0, 0, 0, 0};
        if (ll < 2) {
            int k0 = kt * 32 + lg * 8;
            const float* av = a0g + h * 128 + (ll ? 64 : 0);
            float acc[8] = {0.f, 0.f, 0.f, 0.f, 0.f, 0.f, 0.f, 0.f};
            for (int o = 0; o < 64; ++o) {
                float a = av[o];
#pragma unroll
                for (int j = 0; j < 8; ++j)
                    acc[j] = fmaf(w0[(h * 64 + k0 + j) * 64 + o], a, acc[j]);
            }
#pragma unroll
            for (int j = 0; j < 8; ++j) v[j] = f2bf(acc[j]);
        }
        *(bf16x8*)&u00f[u * 8] = v;
    }
}

#define TBSTRIDE 40

// -------- layer-0 Wh GEMM on MFMA (K=64) + s1/s2 via u-MFMA + Whf B-frags --------
__global__ __launch_bounds__(256) void k_wh1m(const ushort* __restrict__ h0A,
                                              const ushort* __restrict__ W0f,
                                              const ushort* __restrict__ u00f,
                                              ushort* __restrict__ Whf,
                                              float* __restrict__ s1,
                                              float* __restrict__ s2) {
    __shared__ __align__(16) ushort tb[4][64 * TBSTRIDE];
    const int bid = blockIdx.x;
    const int h = bid & 7;
    const int rest = bid >> 3;          // 0..95
    const int b = rest & 15;
    const int chunk = rest >> 4;        // 0..5
    const int bh = b * NH_ + h;

    const int lane = threadIdx.x & 63;
    const int w = threadIdx.x >> 6;
    const int lg = lane >> 4;
    const int ll = lane & 15;

    f32x4 zero4 = {0.f, 0.f, 0.f, 0.f};
    f32x4 acc[2][4];
    f32x4 acc_s[2];
#pragma unroll
    for (int mt = 0; mt < 2; ++mt) {
        acc_s[mt] = zero4;
#pragma unroll
        for (int nt = 0; nt < 4; ++nt) acc[mt][nt] = zero4;
    }

    const int rt0 = b * 48 + chunk * 8 + w * 2;
#pragma unroll
    for (int kt = 0; kt < 2; ++kt) {
        bf16x8 afr[2];
#pragma unroll
        for (int mt = 0; mt < 2; ++mt)
            afr[mt] = *(const bf16x8*)&h0A[(((rt0 + mt) * 2) + kt) * 512 + lane * 8];
        bf16x8 bfr[4];
#pragma unroll
        for (int nt = 0; nt < 4; ++nt)
            bfr[nt] = *(const bf16x8*)&W0f[(((h * 2 + kt) * 4) + nt) * 512 + lane * 8];
        bf16x8 ufr = *(const bf16x8*)&u00f[((h * 2 + kt) * 64 + lane) * 8];
#pragma unroll
        for (int mt = 0; mt < 2; ++mt) {
#pragma unroll
            for (int nt = 0; nt < 4; ++nt)
                acc[mt][nt] = __builtin_amdgcn_mfma_f32_16x16x32_bf16(afr[mt], bfr[nt], acc[mt][nt], 0, 0, 0);
            acc_s[mt] = __builtin_amdgcn_mfma_f32_16x16x32_bf16(afr[mt], ufr, acc_s[mt], 0, 0, 0);
        }
    }

    // s1/s2 direct store (C cols 0/1 of acc_s)
    const int n0 = chunk * 128;
    float* s1b = s1 + bh * N_ + n0 + w * 32;
    float* s2b = s2 + bh * N_ + n0 + w * 32;
    ushort* tbw = tb[w];
#pragma unroll
    for (int mt = 0; mt < 2; ++mt) {
#pragma unroll
        for (int reg = 0; reg < 4; ++reg) {
            const int r32 = mt * 16 + lg * 4 + reg;
            if (ll == 0) s1b[r32] = acc_s[mt][reg];
            else if (ll == 1) s2b[r32] = acc_s[mt][reg];
        }
        // packed transpose store: 4 consecutive rows -> one b64 write
#pragma unroll
        for (int nt = 0; nt < 4; ++nt) {
            bf16x4 pk;
#pragma unroll
            for (int reg = 0; reg < 4; ++reg) pk[reg] = f2bf(acc[mt][nt][reg]);
            *(bf16x4*)&tbw[(nt * 16 + ll) * TBSTRIDE + mt * 16 + lg * 4] = pk;
        }
    }
    __syncthreads();

    const int kt2 = chunk * 4 + w;
#pragma unroll
    for (int nt = 0; nt < 4; ++nt) {
        int c = nt * 16 + ll;
        bf16x8 v = *(const bf16x8*)&tbw[c * TBSTRIDE + lg * 8];
        *(bf16x8*)&Whf[(bh * 24 + kt2) * 2048 + nt * 512 + lane * 8] = v;
    }
}

// ---- fused attention on MFMA; 2 K-tiles per barrier phase; h=bid&7 ----
__global__ __launch_bounds__(256) void k_attn(const ushort* __restrict__ Whf,
                                              const float* __restrict__ s1,
                                              const float* __restrict__ s2,
                                              ushort* __restrict__ hpA) {
    __shared__ __align__(16) float t1s[128];
    __shared__ __align__(16) float t2s[N_];
    __shared__ __align__(16) float dls[128];
    __shared__ __align__(16) ushort hbuf[128 * 64];   // swizzled [row][col]
    __shared__ __align__(16) ushort sbuf[2][4096];    // 2 staged Whf K-tiles
    const int bid = blockIdx.x;
    const int h = bid & 7;
    const int rest = bid >> 3;          // 0..95
    const int b = rest & 15;
    const int nc = rest >> 4;           // 0..5
    const int n0 = nc * 128;
    const int bh = b * NH_ + h;

    const int lane = threadIdx.x & 63;
    const int w = threadIdx.x >> 6;

    const ushort* Wbase = Whf + bh * ((N_ / 32) * 2048);
    // stage tiles 0,1
    gload_lds16(Wbase + threadIdx.x * 8, &sbuf[0][w * 512]);
    gload_lds16(Wbase + 2048 + threadIdx.x * 8, &sbuf[0][2048 + w * 512]);

    const float* s1g = s1 + bh * N_;
    const float* s2g = s2 + bh * N_;
    for (int i = threadIdx.x; i < N_; i += 256) t2s[i] = s2g[i] * LOG2E_;
    if (threadIdx.x < 128) t1s[threadIdx.x] = s1g[n0 + threadIdx.x] * LOG2E_;
    __syncthreads();   // t1s/t2s ready; stage(0) drained

    const int rowbase = w * 32;
    const int lg = lane >> 4;
    const int ll = lane & 15;

    const float t1a = t1s[rowbase + ll];
    const float t1b = t1s[rowbase + 16 + ll];

    f32x4 zero4 = {0.f, 0.f, 0.f, 0.f};
    f32x4 acc[2][4];
    f32x4 dacc[2];
#pragma unroll
    for (int mt = 0; mt < 2; ++mt) {
        dacc[mt] = zero4;
#pragma unroll
        for (int nt = 0; nt < 4; ++nt) acc[mt][nt] = zero4;
    }

    bf16x8 onesB;
#pragma unroll
    for (int j = 0; j < 8; ++j) onesB[j] = (ll == 0) ? (short)0x3F80 : (short)0;

    int cur = 0;
    for (int kp = 0; kp < 12; ++kp) {
        __syncthreads();  // stage(cur) landed; prev reads of buf[cur^1] done
        if (kp + 1 < 12) {
            const ushort* src = Wbase + (kp + 1) * 4096;
            gload_lds16(src + threadIdx.x * 8, &sbuf[cur ^ 1][w * 512]);
            gload_lds16(src + 2048 + threadIdx.x * 8, &sbuf[cur ^ 1][2048 + w * 512]);
        }
#pragma unroll
        for (int sub = 0; sub < 2; ++sub) {
            const int ktile = kp * 2 + sub;
            const ushort* sb = &sbuf[cur][sub * 2048];
            bf16x8 bq[4];
#pragma unroll
            for (int nt = 0; nt < 4; ++nt) bq[nt] = *(const bf16x8*)&sb[nt * 512 + lane * 8];

            const float4 q0 = *(const float4*)&t2s[ktile * 32 + lg * 8];
            const float4 q1 = *(const float4*)&t2s[ktile * 32 + lg * 8 + 4];
            float qv[8] = {q0.x, q0.y, q0.z, q0.w, q1.x, q1.y, q1.z, q1.w};

#pragma unroll
            for (int mt = 0; mt < 2; ++mt) {
                const float t1v = mt ? t1b : t1a;
                bf16x8 af;
#pragma unroll
                for (int j = 0; j < 8; ++j) {
                    float e = t1v + qv[j];
                    e = fmaxf(e, 0.2f * e);   // leaky_relu (log2-scaled; scale>0 commutes)
                    af[j] = f2bf(exp2f(e));
                }
                dacc[mt] = __builtin_amdgcn_mfma_f32_16x16x32_bf16(af, onesB, dacc[mt], 0, 0, 0);
#pragma unroll
                for (int nt = 0; nt < 4; ++nt)
                    acc[mt][nt] = __builtin_amdgcn_mfma_f32_16x16x32_bf16(af, bq[nt], acc[mt][nt], 0, 0, 0);
            }
        }
        cur ^= 1;
    }

#pragma unroll
    for (int mt = 0; mt < 2; ++mt) {
        if (ll == 0) {
#pragma unroll
            for (int reg = 0; reg < 4; ++reg)
                dls[rowbase + mt * 16 + lg * 4 + reg] = dacc[mt][reg];
        }
    }
    __syncthreads();

    // scale + swizzled bf16 store to LDS (row stride 128B, swz<128: bijective)
    char* hb8 = (char*)hbuf;
#pragma unroll
    for (int mt = 0; mt < 2; ++mt) {
#pragma unroll
        for (int reg = 0; reg < 4; ++reg) {
            const int row = rowbase + mt * 16 + lg * 4 + reg;
            const float inv = 1.0f / dls[row];
            const int swz = (row & 7) << 4;
#pragma unroll
            for (int nt = 0; nt < 4; ++nt) {
                int c = nt * 16 + ll;
                *(ushort*)(hb8 + row * 128 + ((c * 2) ^ swz)) =
                    (ushort)f2bf(acc[mt][nt][reg] * inv);
            }
        }
    }
    __syncthreads();

    // fragment read + coalesced global store
    // hpA[rtg][kc][lane][8]; value = hp[rtg*16+(l&15)][kc*32+(l>>4)*8+j]
#pragma unroll
    for (int rt2 = 0; rt2 < 2; ++rt2) {
#pragma unroll
        for (int kc = 0; kc < 2; ++kc) {
            const int rtl = w * 2 + rt2;
            const int row = rtl * 16 + ll;
            bf16x8 v = *(const bf16x8*)(hb8 + row * 128 +
                                        (((kc * 64 + lg * 16)) ^ ((row & 7) << 4)));
            const int rtg = b * 48 + nc * 8 + rtl;
            *(bf16x8*)&hpA[((rtg * 16) + (h * 2 + kc)) * 512 + lane * 8] = v;
        }
    }
}

// -------- layer-1 Wh GEMM on MFMA + s1/s2 via u-MFMA + Whf frags; W1f staged --------
__global__ __launch_bounds__(256) void k_wh2(const ushort* __restrict__ hpA,
                                             const ushort* __restrict__ W1f,
                                             const ushort* __restrict__ u01f,
                                             ushort* __restrict__ Whf,
                                             float* __restrict__ s1,
                                             float* __restrict__ s2) {
    __shared__ __align__(16) ushort tb[4][64 * TBSTRIDE];
    __shared__ __align__(16) ushort sbuf[2][2048];
    const int bid = blockIdx.x;
    const int h = bid & 7;
    const int rest = bid >> 3;
    const int b = rest & 15;
    const int chunk = rest >> 4;
    const int bh = b * NH_ + h;

    const int lane = threadIdx.x & 63;
    const int w = threadIdx.x >> 6;
    const int lg = lane >> 4;
    const int ll = lane & 15;

    f32x4 zero4 = {0.f, 0.f, 0.f, 0.f};
    f32x4 acc[2][4];
    f32x4 acc_s[2];
#pragma unroll
    for (int mt = 0; mt < 2; ++mt) {
        acc_s[mt] = zero4;
#pragma unroll
        for (int nt = 0; nt < 4; ++nt) acc[mt][nt] = zero4;
    }

    const ushort* W1base = W1f + h * 16 * 2048;
    gload_lds16(W1base + threadIdx.x * 8, &sbuf[0][w * 512]);

    const int rt0 = b * 48 + chunk * 8 + w * 2;
    int cur = 0;
    for (int kt = 0; kt < 16; ++kt) {
        __syncthreads();
        if (kt + 1 < 16)
            gload_lds16(W1base + (kt + 1) * 2048 + threadIdx.x * 8, &sbuf[cur ^ 1][w * 512]);
        bf16x8 afr[2];
#pragma unroll
        for (int mt = 0; mt < 2; ++mt)
            afr[mt] = *(const bf16x8*)&hpA[(((rt0 + mt) * 16) + kt) * 512 + lane * 8];
        bf16x8 ufr = *(const bf16x8*)&u01f[((h * 16 + kt) * 64 + lane) * 8];
        const ushort* sb = sbuf[cur];
        bf16x8 bfr[4];
#pragma unroll
        for (int nt = 0; nt < 4; ++nt)
            bfr[nt] = *(const bf16x8*)&sb[nt * 512 + lane * 8];
#pragma unroll
        for (int mt = 0; mt < 2; ++mt) {
#pragma unroll
            for (int nt = 0; nt < 4; ++nt)
                acc[mt][nt] = __builtin_amdgcn_mfma_f32_16x16x32_bf16(afr[mt], bfr[nt], acc[mt][nt], 0, 0, 0);
            acc_s[mt] = __builtin_amdgcn_mfma_f32_16x16x32_bf16(afr[mt], ufr, acc_s[mt], 0, 0, 0);
        }
        cur ^= 1;
    }

    const int n0 = chunk * 128;
    float* s1b = s1 + bh * N_ + n0 + w * 32;
    float* s2b = s2 + bh * N_ + n0 + w * 32;
    ushort* tbw = tb[w];
#pragma unroll
    for (int mt = 0; mt < 2; ++mt) {
#pragma unroll
        for (int reg = 0; reg < 4; ++reg) {
            const int r32 = mt * 16 + lg * 4 + reg;
            if (ll == 0) s1b[r32] = acc_s[mt][reg];
            else if (ll == 1) s2b[r32] = acc_s[mt][reg];
        }
#pragma unroll
        for (int nt = 0; nt < 4; ++nt) {
            bf16x4 pk;
#pragma unroll
            for (int reg = 0; reg < 4; ++reg) pk[reg] = f2bf(acc[mt][nt][reg]);
            *(bf16x4*)&tbw[(nt * 16 + ll) * TBSTRIDE + mt * 16 + lg * 4] = pk;
        }
    }
    __syncthreads();

    const int kt2 = chunk * 4 + w;
#pragma unroll
    for (int nt = 0; nt < 4; ++nt) {
        int c = nt * 16 + ll;
        bf16x8 v = *(const bf16x8*)&tbw[c * TBSTRIDE + lg * 8];
        *(bf16x8*)&Whf[(bh * 24 + kt2) * 2048 + nt * 512 + lane * 8] = v;
    }
}

// -------- output projection on MFMA; pwf LDS-staged (2-phase dbuf) --------
__global__ __launch_bounds__(256) void k_projm(const ushort* __restrict__ hpA,
                                               const ushort* __restrict__ pwf,
                                               const float* __restrict__ bias,
                                               float* __restrict__ out) {
    __shared__ __align__(16) ushort sbuf[2][4096];
    const int blk = blockIdx.x;          // 384 blocks, 32 rows each
    const int lane = threadIdx.x & 63;
    const int w = threadIdx.x >> 6;
    const int wrow = w >> 1, wcol = w & 1;
    const int lg = lane >> 4;
    const int ll = lane & 15;

    f32x4 zero4 = {0.f, 0.f, 0.f, 0.f};
    f32x4 acc[4];
#pragma unroll
    for (int nt = 0; nt < 4; ++nt) acc[nt] = zero4;

    gload_lds16(pwf + threadIdx.x * 8, &sbuf[0][w * 512]);
    gload_lds16(pwf + 2048 + threadIdx.x * 8, &sbuf[0][2048 + w * 512]);

    const int rt = blk * 2 + wrow;
    int cur = 0;
    for (int kt = 0; kt < 16; ++kt) {
        __syncthreads();
        if (kt + 1 < 16) {
            const ushort* row = pwf + (kt + 1) * 4096;
            gload_lds16(row + threadIdx.x * 8, &sbuf[cur ^ 1][w * 512]);
            gload_lds16(row + 2048 + threadIdx.x * 8, &sbuf[cur ^ 1][2048 + w * 512]);
        }
        bf16x8 afr = *(const bf16x8*)&hpA[((rt * 16) + kt) * 512 + lane * 8];
        const ushort* sb = sbuf[cur];
        bf16x8 bfr[4];
#pragma unroll
        for (int nt = 0; nt < 4; ++nt)
            bfr[nt] = *(const bf16x8*)&sb[(wcol * 4 + nt) * 512 + lane * 8];
#pragma unroll
        for (int nt = 0; nt < 4; ++nt)
            acc[nt] = __builtin_amdgcn_mfma_f32_16x16x32_bf16(afr, bfr[nt], acc[nt], 0, 0, 0);
        cur ^= 1;
    }

#pragma unroll
    for (int reg = 0; reg < 4; ++reg) {
        const int row = blk * 32 + wrow * 16 + lg * 4 + reg;
#pragma unroll
        for (int nt = 0; nt < 4; ++nt) {
            const int col = wcol * 64 + nt * 16 + ll;
            out[row * EMB_ + col] = acc[nt][reg] + bias[col];
        }
    }
}

extern "C" void kernel_launch(void* const* d_in, const int* in_sizes, int n_in,
                              void* d_out, int out_size, void* d_ws, size_t ws_size,
                              hipStream_t stream) {
    const float* x    = (const float*)d_in[0];
    const float* ip_w = (const float*)d_in[1];
    const float* ip_b = (const float*)d_in[2];
    const float* gw0  = (const float*)d_in[3];
    const float* ga0  = (const float*)d_in[4];
    const float* gw1  = (const float*)d_in[5];
    const float* ga1  = (const float*)d_in[6];
    const float* pw   = (const float*)d_in[7];
    const float* pb   = (const float*)d_in[8];
    float* out = (float*)d_out;

    ushort* h0A = (ushort*)d_ws;                      // 786432 us
    ushort* Whf = h0A + 786432;                       // 6291456 us
    float* s1 = (float*)(Whf + 6291456);              // 98304 f
    float* s2 = s1 + B_ * NH_ * N_;                   // 98304 f
    ushort* hpA = (ushort*)(s2 + B_ * NH_ * N_);      // 6291456 us
    ushort* W1f = hpA + 6291456;                      // 262144 us
    ushort* pwf = W1f + 262144;                       // 65536 us
    ushort* W0f = pwf + 65536;                        // 32768 us
    ushort* u01f = W0f + 32768;                       // 65536 us
    ushort* u00f = u01f + 65536;                      // 8192 us

    const int gat_blocks = 768;   // 8 h (XCD) x 16 b x 6 chunks

    k_prep<<<596, 256, 0, stream>>>(x, ip_w, ip_b, gw1, pw, gw0, ga1, ga0,
                                    h0A, W1f, pwf, W0f, u01f, u00f);
    k_wh1m<<<gat_blocks, 256, 0, stream>>>(h0A, W0f, u00f, Whf, s1, s2);
    k_attn<<<gat_blocks, 256, 0, stream>>>(Whf, s1, s2, hpA);
    k_wh2<<<gat_blocks, 256, 0, stream>>>(hpA, W1f, u01f, Whf, s1, s2);
    k_attn<<<gat_blocks, 256, 0, stream>>>(Whf, s1, s2, hpA);
    k_projm<<<(B_ * N_) / 32, 256, 0, stream>>>(hpA, pwf, pb, out);
}

// Round 8
// 177.078 us; speedup vs baseline: 1.0570x; 1.0570x over previous
//
#include <hip/hip_runtime.h>
#include <hip/hip_bf16.h>

// GAT encoder: B=16, N=768, IN=16, HID=64, HEADS=8, EMB=128, 2 GAT layers.
// Round 8: per-layer fused mega-kernel. Block = (b,h,half) computes full
// 768x64 Wh into LDS (B-fragment layout, j-packed b64 writes), s1/s2 via
// u-MFMA into LDS, then attention for its 384 query rows. Whf/s1/s2 never
// hit global. W1f staged in LDS (aliased with Whf region pre-write); hbuf
// epilogue aliases the same region post-read. u computed by a coalesced
// reduction kernel with LOG2E folded in.
//
// ws: h0A us[786432] | hpA0 us[6291456] | hpA1 us[6291456] | W1f us[262144]
//     | pwf us[65536] | W0f us[32768] | u1s f[8192] | u0s f[1024]

#define B_ 16
#define N_ 768
#define IN_DIM_ 16
#define HID_ 64
#define EMB_ 128
#define NH_ 8
#define LOG2E_ 1.4426950408889634f

typedef __attribute__((ext_vector_type(4))) float f32x4;
typedef __attribute__((ext_vector_type(8))) short bf16x8;
typedef __attribute__((ext_vector_type(4))) short bf16x4;

typedef __attribute__((address_space(1))) const unsigned int gu32;
typedef __attribute__((address_space(3))) unsigned int lu32;

static __device__ __forceinline__ void gload_lds16(const void* g, void* l) {
    // async global->LDS, 16B per lane; LDS dest = wave-uniform base + lane*16
    __builtin_amdgcn_global_load_lds((gu32*)g, (lu32*)l, 16, 0, 0);
}

static __device__ __forceinline__ short f2bf(float x) {
    __hip_bfloat16 b = __float2bfloat16(x);
    return *reinterpret_cast<short*>(&b);
}

// ---- prep: h0A A-fragments + W1f/pwf/W0f B-fragments (verified round 6) ----
__global__ __launch_bounds__(256) void k_prep(const float* __restrict__ x,
                                              const float* __restrict__ ipw,
                                              const float* __restrict__ ipb,
                                              const float* __restrict__ w1,
                                              const float* __restrict__ pw,
                                              const float* __restrict__ w0,
                                              ushort* __restrict__ h0A,
                                              ushort* __restrict__ W1f,
                                              ushort* __restrict__ pwf,
                                              ushort* __restrict__ W0f) {
    if (blockIdx.x < 384) {
        const int t = blockIdx.x * 256 + threadIdx.x;  // < 98304
        const int lane = t & 63;
        const int kt = (t >> 6) & 1;
        const int rtg = t >> 7;
        const int row = rtg * 16 + (lane & 15);
        const int k0 = kt * 32 + (lane >> 4) * 8;
        const float* xr = x + row * IN_DIM_;
        float xv[IN_DIM_];
#pragma unroll
        for (int f = 0; f < IN_DIM_; ++f) xv[f] = xr[f];
        bf16x8 v;
#pragma unroll
        for (int j = 0; j < 8; ++j) {
            float acc = ipb[k0 + j];
#pragma unroll
            for (int f = 0; f < IN_DIM_; ++f) acc = fmaf(xv[f], ipw[f * HID_ + k0 + j], acc);
            v[j] = f2bf(acc);
        }
        *(bf16x8*)&h0A[t * 8] = v;
        return;
    }
    int t = (blockIdx.x - 384) * 256 + threadIdx.x;  // < 45056
    if (t < 32768) {
        // W1f[h][kt16][nt4][lane][8] = w1[h][kt*32+(l>>4)*8+j][nt*16+(l&15)]
        int lane = t & 63, nt = (t >> 6) & 3, kt = (t >> 8) & 15, h = t >> 12;
        int k0 = kt * 32 + (lane >> 4) * 8;
        int col = nt * 16 + (lane & 15);
        const float* src = w1 + (h * 512 + k0) * 64 + col;
        bf16x8 v;
#pragma unroll
        for (int j = 0; j < 8; ++j) v[j] = f2bf(src[j * 64]);
        *(bf16x8*)&W1f[t * 8] = v;
    } else if (t < 40960) {
        int u = t - 32768;  // < 8192
        int lane = u & 63, nt = (u >> 6) & 7, kt = u >> 9;
        int k0 = kt * 32 + (lane >> 4) * 8;
        int col = nt * 16 + (lane & 15);
        const float* src = pw + k0 * 128 + col;
        bf16x8 v;
#pragma unroll
        for (int j = 0; j < 8; ++j) v[j] = f2bf(src[j * 128]);
        *(bf16x8*)&pwf[u * 8] = v;
    } else if (t < 45056) {
        int u = t - 40960;  // < 4096
        int lane = u & 63, nt = (u >> 6) & 3, kt = (u >> 8) & 1, h = u >> 9;
        int k0 = kt * 32 + (lane >> 4) * 8;
        int col = nt * 16 + (lane & 15);
        const float* src = w0 + (h * 64 + k0) * 64 + col;
        bf16x8 v;
#pragma unroll
        for (int j = 0; j < 8; ++j) v[j] = f2bf(src[j * 64]);
        *(bf16x8*)&W0f[u * 8] = v;
    }
}

// ---- u = (W·a) * LOG2E, coalesced block reduction ----
// u1s[(h*2+sel)*512 + k] for layer 1; u0s[(h*2+sel)*64 + k] for layer 0.
__global__ __launch_bounds__(256) void k_ufrag(const float* __restrict__ w1,
                                               const float* __restrict__ a1g,
                                               const float* __restrict__ w0,
                                               const float* __restrict__ a0g,
                                               float* __restrict__ u1s,
                                               float* __restrict__ u0s) {
    const int bid = blockIdx.x;
    const int tid = threadIdx.x;
    const int kl = tid >> 3;       // 0..31
    const int og = tid & 7;        // 0..7 (8-float segments)
    const float* W;
    const float* A;
    float* U;
    if (bid < 256) {               // layer 1: (h, kt<16, sel)
        int sel = bid & 1, kt = (bid >> 1) & 15, h = bid >> 5;
        W = w1 + (h * 512 + kt * 32 + kl) * 64;
        A = a1g + h * 128 + sel * 64;
        U = u1s + (h * 2 + sel) * 512 + kt * 32 + kl;
    } else {                       // layer 0: (h, kt<2, sel)
        int u = bid - 256;
        int sel = u & 1, kt = (u >> 1) & 1, h = u >> 2;
        W = w0 + (h * 64 + kt * 32 + kl) * 64;
        A = a0g + h * 128 + sel * 64;
        U = u0s + (h * 2 + sel) * 64 + kt * 32 + kl;
    }
    float4 w0v = *(const float4*)&W[og * 8];
    float4 w1v = *(const float4*)&W[og * 8 + 4];
    float4 a0v = *(const float4*)&A[og * 8];
    float4 a1v = *(const float4*)&A[og * 8 + 4];
    float r = w0v.x * a0v.x + w0v.y * a0v.y + w0v.z * a0v.z + w0v.w * a0v.w +
              w1v.x * a1v.x + w1v.y * a1v.y + w1v.z * a1v.z + w1v.w * a1v.w;
    r += __shfl_xor(r, 1);
    r += __shfl_xor(r, 2);
    r += __shfl_xor(r, 4);
    if (og == 0) *U = r * LOG2E_;
}

// ---- fused GAT layer: block (b,h,half) -> Wh in LDS -> attention ----
// KT = K/32 of the Wh GEMM: 2 (layer 0, A=h0A, B=W0f) or 16 (layer 1, A=hpA0,
// B=W1f staged in LDS). Output: hpA A-fragments for the block's 384 rows.
template <int KT>
__global__ __launch_bounds__(512, 2) void k_gat(const ushort* __restrict__ Afrag,
                                                const ushort* __restrict__ Bfrag,
                                                const float* __restrict__ us,
                                                ushort* __restrict__ hpA) {
    __shared__ __align__(16) char smem[98304];  // Whf frags; aliases W1f-stage / hbuf
    __shared__ __align__(16) float s1s[N_];
    __shared__ __align__(16) float s2s[N_];
    ushort* whf = (ushort*)smem;

    const int bid = blockIdx.x;
    const int half = bid & 1;
    const int h = (bid >> 1) & 7;
    const int b = bid >> 4;

    const int tid = threadIdx.x;
    const int lane = tid & 63;
    const int w = tid >> 6;       // 0..7
    const int lg = lane >> 4;
    const int ll = lane & 15;

    // ================= Phase A: Wh(768x64) + s1/s2 =================
    if constexpr (KT == 16) {
        const ushort* src = Bfrag + h * 16 * 2048;   // 64KB W1f[h]
#pragma unroll
        for (int r = 0; r < 8; ++r)
            gload_lds16(src + r * 4096 + tid * 8, (char*)smem + r * 8192 + w * 1024);
        __syncthreads();
    }

    f32x4 acc[6][4];
    f32x4 accs[6];
#pragma unroll
    for (int i = 0; i < 6; ++i) {
        accs[i] = (f32x4){0.f, 0.f, 0.f, 0.f};
#pragma unroll
        for (int nt = 0; nt < 4; ++nt) acc[i][nt] = (f32x4){0.f, 0.f, 0.f, 0.f};
    }

    for (int kt = 0; kt < KT; ++kt) {
        bf16x8 bfr[4];
        if constexpr (KT == 16) {
#pragma unroll
            for (int nt = 0; nt < 4; ++nt)
                bfr[nt] = *(const bf16x8*)&whf[kt * 2048 + nt * 512 + lane * 8];
        } else {
#pragma unroll
            for (int nt = 0; nt < 4; ++nt)
                bfr[nt] = *(const bf16x8*)&Bfrag[((h * 2 + kt) * 4 + nt) * 512 + lane * 8];
        }
        bf16x8 ufr = {0, 0, 0, 0, 0, 0, 0, 0};
        if (ll < 2) {
            const float* uq = us + (h * 2 + ll) * (KT * 32) + kt * 32 + lg * 8;
            float4 a0 = *(const float4*)uq;
            float4 a1 = *(const float4*)(uq + 4);
            ufr[0] = f2bf(a0.x); ufr[1] = f2bf(a0.y); ufr[2] = f2bf(a0.z); ufr[3] = f2bf(a0.w);
            ufr[4] = f2bf(a1.x); ufr[5] = f2bf(a1.y); ufr[6] = f2bf(a1.z); ufr[7] = f2bf(a1.w);
        }
#pragma unroll
        for (int i = 0; i < 6; ++i) {
            const int rt = w * 6 + i;
            bf16x8 afr = *(const bf16x8*)&Afrag[((b * 48 + rt) * KT + kt) * 512 + lane * 8];
#pragma unroll
            for (int nt = 0; nt < 4; ++nt)
                acc[i][nt] = __builtin_amdgcn_mfma_f32_16x16x32_bf16(afr, bfr[nt], acc[i][nt], 0, 0, 0);
            accs[i] = __builtin_amdgcn_mfma_f32_16x16x32_bf16(afr, ufr, accs[i], 0, 0, 0);
        }
    }
    if constexpr (KT == 16) __syncthreads();  // staged-B reads done before overwrite

    // Wh fragments -> LDS (j-packed b64: rows lg*4..+3 are 4 consecutive j at
    // fixed dest lane lp), s1/s2 -> LDS.
#pragma unroll
    for (int i = 0; i < 6; ++i) {
        const int rt = w * 6 + i;
        const int lp = ((rt * 2 + (lg >> 1)) & 3) * 16 + ll;
        const int j0 = 4 * (lg & 1);
#pragma unroll
        for (int nt = 0; nt < 4; ++nt) {
            bf16x4 pk;
#pragma unroll
            for (int reg = 0; reg < 4; ++reg) pk[reg] = f2bf(acc[i][nt][reg]);
            *(bf16x4*)&whf[(((rt >> 1) * 4 + nt) * 64 + lp) * 8 + j0] = pk;
        }
#pragma unroll
        for (int reg = 0; reg < 4; ++reg) {
            const int row = rt * 16 + lg * 4 + reg;
            if (ll == 0) s1s[row] = accs[i][reg];
            else if (ll == 1) s2s[row] = accs[i][reg];
        }
    }
    __syncthreads();

    // ================= Phase B: attention, rows [half*384 + w*48, +48) =================
    const int qbase = half * 384 + w * 48;
    float t1v[3];
#pragma unroll
    for (int mt = 0; mt < 3; ++mt) t1v[mt] = s1s[qbase + mt * 16 + ll];

    f32x4 pacc[3][4];
    f32x4 dacc[3];
#pragma unroll
    for (int mt = 0; mt < 3; ++mt) {
        dacc[mt] = (f32x4){0.f, 0.f, 0.f, 0.f};
#pragma unroll
        for (int nt = 0; nt < 4; ++nt) pacc[mt][nt] = (f32x4){0.f, 0.f, 0.f, 0.f};
    }
    bf16x8 onesB;
#pragma unroll
    for (int j = 0; j < 8; ++j) onesB[j] = (ll == 0) ? (short)0x3F80 : (short)0;

    for (int kt = 0; kt < 24; ++kt) {
        bf16x8 bq[4];
#pragma unroll
        for (int nt = 0; nt < 4; ++nt)
            bq[nt] = *(const bf16x8*)&whf[kt * 2048 + nt * 512 + lane * 8];
        const float4 q0 = *(const float4*)&s2s[kt * 32 + lg * 8];
        const float4 q1 = *(const float4*)&s2s[kt * 32 + lg * 8 + 4];
        float qv[8] = {q0.x, q0.y, q0.z, q0.w, q1.x, q1.y, q1.z, q1.w};
#pragma unroll
        for (int mt = 0; mt < 3; ++mt) {
            bf16x8 af;
#pragma unroll
            for (int j = 0; j < 8; ++j) {
                float e = t1v[mt] + qv[j];
                e = fmaxf(e, 0.2f * e);   // leaky_relu (log2-scaled; scale>0 commutes)
                af[j] = f2bf(exp2f(e));
            }
            dacc[mt] = __builtin_amdgcn_mfma_f32_16x16x32_bf16(af, onesB, dacc[mt], 0, 0, 0);
#pragma unroll
            for (int nt = 0; nt < 4; ++nt)
                pacc[mt][nt] = __builtin_amdgcn_mfma_f32_16x16x32_bf16(af, bq[nt], pacc[mt][nt], 0, 0, 0);
        }
    }
    __syncthreads();   // all whf reads done; reuse smem as hbuf (384 rows x 128B)

    char* hb8 = smem;
#pragma unroll
    for (int mt = 0; mt < 3; ++mt) {
#pragma unroll
        for (int reg = 0; reg < 4; ++reg) {
            const int rl = w * 48 + mt * 16 + lg * 4 + reg;   // 0..383 local row
            const float dv = __shfl(dacc[mt][reg], lane & 0x30);  // rowsum at ll==0
            const float inv = 1.0f / dv;
            const int swz = (rl & 7) << 4;
#pragma unroll
            for (int nt = 0; nt < 4; ++nt) {
                int c = nt * 16 + ll;
                *(ushort*)(hb8 + rl * 128 + ((c * 2) ^ swz)) =
                    (ushort)f2bf(pacc[mt][nt][reg] * inv);
            }
        }
    }
    __syncthreads();

    // fragment read + coalesced global store (verified epilogue, 3 rtiles/wave)
#pragma unroll
    for (int rt2 = 0; rt2 < 3; ++rt2) {
#pragma unroll
        for (int kc = 0; kc < 2; ++kc) {
            const int rtl = w * 3 + rt2;
            const int row = rtl * 16 + ll;
            bf16x8 v = *(const bf16x8*)(hb8 + row * 128 +
                                        ((kc * 64 + lg * 16) ^ ((row & 7) << 4)));
            const int rtg = b * 48 + half * 24 + rtl;
            *(bf16x8*)&hpA[((rtg * 16) + (h * 2 + kc)) * 512 + lane * 8] = v;
        }
    }
}

// -------- output projection on MFMA (verified round 5) --------
__global__ __launch_bounds__(256) void k_projm(const ushort* __restrict__ hpA,
                                               const ushort* __restrict__ pwf,
                                               const float* __restrict__ bias,
                                               float* __restrict__ out) {
    const int blk = blockIdx.x;          // 384 blocks, 32 rows each
    const int lane = threadIdx.x & 63;
    const int w = threadIdx.x >> 6;
    const int wrow = w >> 1, wcol = w & 1;
    const int lg = lane >> 4;
    const int ll = lane & 15;

    f32x4 acc[4];
#pragma unroll
    for (int nt = 0; nt < 4; ++nt) acc[nt] = (f32x4){0.f, 0.f, 0.f, 0.f};

    const int rt = blk * 2 + wrow;
    for (int kt = 0; kt < 16; ++kt) {
        bf16x8 afr = *(const bf16x8*)&hpA[((rt * 16) + kt) * 512 + lane * 8];
        bf16x8 bfr[4];
#pragma unroll
        for (int nt = 0; nt < 4; ++nt)
            bfr[nt] = *(const bf16x8*)&pwf[((kt * 8) + wcol * 4 + nt) * 512 + lane * 8];
#pragma unroll
        for (int nt = 0; nt < 4; ++nt)
            acc[nt] = __builtin_amdgcn_mfma_f32_16x16x32_bf16(afr, bfr[nt], acc[nt], 0, 0, 0);
    }

#pragma unroll
    for (int reg = 0; reg < 4; ++reg) {
        const int row = blk * 32 + wrow * 16 + lg * 4 + reg;
#pragma unroll
        for (int nt = 0; nt < 4; ++nt) {
            const int col = wcol * 64 + nt * 16 + ll;
            out[row * EMB_ + col] = acc[nt][reg] + bias[col];
        }
    }
}

extern "C" void kernel_launch(void* const* d_in, const int* in_sizes, int n_in,
                              void* d_out, int out_size, void* d_ws, size_t ws_size,
                              hipStream_t stream) {
    const float* x    = (const float*)d_in[0];
    const float* ip_w = (const float*)d_in[1];
    const float* ip_b = (const float*)d_in[2];
    const float* gw0  = (const float*)d_in[3];
    const float* ga0  = (const float*)d_in[4];
    const float* gw1  = (const float*)d_in[5];
    const float* ga1  = (const float*)d_in[6];
    const float* pw   = (const float*)d_in[7];
    const float* pb   = (const float*)d_in[8];
    float* out = (float*)d_out;

    ushort* h0A  = (ushort*)d_ws;        // 786432 us
    ushort* hpA0 = h0A + 786432;         // 6291456 us
    ushort* hpA1 = hpA0 + 6291456;       // 6291456 us
    ushort* W1f  = hpA1 + 6291456;       // 262144 us
    ushort* pwf  = W1f + 262144;         // 65536 us
    ushort* W0f  = pwf + 65536;          // 32768 us
    float*  u1s  = (float*)(W0f + 32768);  // 8192 f
    float*  u0s  = u1s + 8192;             // 1024 f

    k_prep<<<560, 256, 0, stream>>>(x, ip_w, ip_b, gw1, pw, gw0, h0A, W1f, pwf, W0f);
    k_ufrag<<<288, 256, 0, stream>>>(gw1, ga1, gw0, ga0, u1s, u0s);
    k_gat<2><<<256, 512, 0, stream>>>(h0A, W0f, u0s, hpA0);
    k_gat<16><<<256, 512, 0, stream>>>(hpA0, W1f, u1s, hpA1);
    k_projm<<<(B_ * N_) / 32, 256, 0, stream>>>(hpA1, pwf, pb, out);
}

// Round 9
// 146.578 us; speedup vs baseline: 1.2769x; 1.2081x over previous
//
#include <hip/hip_runtime.h>
#include <hip/hip_bf16.h>

// GAT encoder: B=16, N=768, IN=16, HID=64, HEADS=8, EMB=128, 2 GAT layers.
// Round 9: fused k_gat v2.
//  - softmax via exp-domain factorization: p = max(e1[n]*e2[m], f1[n]*f2[m])
//    (2^max(x,.2x) = max(2^x, 2^{.2x})) -- no exp2 in the inner loop.
//  - u = (W·a)*LOG2E precomputed as zero-padded bf16 B-fragments in k_prep.
//  - 1-deep even/odd register pipeline for afr (global) and bq/e2/f2 loads.
//  - b-aligned XCD mapping (bid&15 = b) to cut cross-XCD refetch.
//
// ws: h0A us[786432] | hpA0 us[6291456] | hpA1 us[6291456] | W1f us[262144]
//     | pwf us[65536] | W0f us[32768] | u1F us[65536] | u0F us[8192]

#define B_ 16
#define N_ 768
#define IN_DIM_ 16
#define HID_ 64
#define EMB_ 128
#define NH_ 8
#define LOG2E_ 1.4426950408889634f

typedef __attribute__((ext_vector_type(4))) float f32x4;
typedef __attribute__((ext_vector_type(8))) short bf16x8;
typedef __attribute__((ext_vector_type(4))) short bf16x4;

typedef __attribute__((address_space(1))) const unsigned int gu32;
typedef __attribute__((address_space(3))) unsigned int lu32;

static __device__ __forceinline__ void gload_lds16(const void* g, void* l) {
    __builtin_amdgcn_global_load_lds((gu32*)g, (lu32*)l, 16, 0, 0);
}

static __device__ __forceinline__ short f2bf(float x) {
    __hip_bfloat16 b = __float2bfloat16(x);
    return *reinterpret_cast<short*>(&b);
}

// ---- prep: h0A A-frags + W1f/pwf/W0f B-frags + u1F/u0F u-fragments ----
__global__ __launch_bounds__(256) void k_prep(const float* __restrict__ x,
                                              const float* __restrict__ ipw,
                                              const float* __restrict__ ipb,
                                              const float* __restrict__ w1,
                                              const float* __restrict__ pw,
                                              const float* __restrict__ w0,
                                              const float* __restrict__ a1g,
                                              const float* __restrict__ a0g,
                                              ushort* __restrict__ h0A,
                                              ushort* __restrict__ W1f,
                                              ushort* __restrict__ pwf,
                                              ushort* __restrict__ W0f,
                                              ushort* __restrict__ u1F,
                                              ushort* __restrict__ u0F) {
    const int bid = blockIdx.x;
    const int tid = threadIdx.x;
    if (bid < 384) {
        const int t = bid * 256 + tid;  // < 98304
        const int lane = t & 63;
        const int kt = (t >> 6) & 1;
        const int rtg = t >> 7;
        const int row = rtg * 16 + (lane & 15);
        const int k0 = kt * 32 + (lane >> 4) * 8;
        const float* xr = x + row * IN_DIM_;
        float xv[IN_DIM_];
#pragma unroll
        for (int f = 0; f < IN_DIM_; ++f) xv[f] = xr[f];
        bf16x8 v;
#pragma unroll
        for (int j = 0; j < 8; ++j) {
            float acc = ipb[k0 + j];
#pragma unroll
            for (int f = 0; f < IN_DIM_; ++f) acc = fmaf(xv[f], ipw[f * HID_ + k0 + j], acc);
            v[j] = f2bf(acc);
        }
        *(bf16x8*)&h0A[t * 8] = v;
        return;
    }
    if (bid < 560) {
        int t = (bid - 384) * 256 + tid;  // < 45056
        if (t < 32768) {
            int lane = t & 63, nt = (t >> 6) & 3, kt = (t >> 8) & 15, h = t >> 12;
            int k0 = kt * 32 + (lane >> 4) * 8;
            int col = nt * 16 + (lane & 15);
            const float* src = w1 + (h * 512 + k0) * 64 + col;
            bf16x8 v;
#pragma unroll
            for (int j = 0; j < 8; ++j) v[j] = f2bf(src[j * 64]);
            *(bf16x8*)&W1f[t * 8] = v;
        } else if (t < 40960) {
            int u = t - 32768;
            int lane = u & 63, nt = (u >> 6) & 7, kt = u >> 9;
            int k0 = kt * 32 + (lane >> 4) * 8;
            int col = nt * 16 + (lane & 15);
            const float* src = pw + k0 * 128 + col;
            bf16x8 v;
#pragma unroll
            for (int j = 0; j < 8; ++j) v[j] = f2bf(src[j * 128]);
            *(bf16x8*)&pwf[u * 8] = v;
        } else {
            int u = t - 40960;
            int lane = u & 63, nt = (u >> 6) & 3, kt = (u >> 8) & 1, h = u >> 9;
            int k0 = kt * 32 + (lane >> 4) * 8;
            int col = nt * 16 + (lane & 15);
            const float* src = w0 + (h * 64 + k0) * 64 + col;
            bf16x8 v;
#pragma unroll
            for (int j = 0; j < 8; ++j) v[j] = f2bf(src[j * 64]);
            *(bf16x8*)&W0f[u * 8] = v;
        }
        return;
    }
    // u-fragment blocks: one block per (layer,h,kt) -> zero + fill ll<2 lanes
    int ub = bid - 560;  // < 144
    const float* W;
    const float* A;
    ushort* dst;
    if (ub < 128) {
        int h = ub >> 4, kt = ub & 15;
        W = w1 + (h * 512 + kt * 32) * 64;
        A = a1g + h * 128;
        dst = u1F + (h * 16 + kt) * 512;
    } else {
        int v2 = ub - 128;
        int h = v2 >> 1, kt = v2 & 1;
        W = w0 + (h * 64 + kt * 32) * 64;
        A = a0g + h * 128;
        dst = u0F + (h * 2 + kt) * 512;
    }
    ((unsigned int*)dst)[tid] = 0u;   // zero 512 ushorts
    __syncthreads();
    const int sel = tid >> 7, kl = (tid >> 2) & 31, og4 = tid & 3;
    const float* Wr = W + kl * 64 + og4 * 16;
    const float* Ar = A + sel * 64 + og4 * 16;
    float r = 0.f;
#pragma unroll
    for (int q = 0; q < 4; ++q) {
        float4 wv = *(const float4*)&Wr[q * 4];
        float4 av = *(const float4*)&Ar[q * 4];
        r += wv.x * av.x + wv.y * av.y + wv.z * av.z + wv.w * av.w;
    }
    r += __shfl_xor(r, 1);
    r += __shfl_xor(r, 2);
    if (og4 == 0)
        dst[((kl >> 3) * 16 + sel) * 8 + (kl & 7)] = (ushort)f2bf(r * LOG2E_);
}

// ---- fused GAT layer: block (b,h,half) -> Wh in LDS -> attention ----
template <int KT>
__global__ __launch_bounds__(512, 2) void k_gat(const ushort* __restrict__ Afrag,
                                                const ushort* __restrict__ Bfrag,
                                                const ushort* __restrict__ uF,
                                                ushort* __restrict__ hpA) {
    __shared__ __align__(16) char smem[98304];  // Whf frags; aliases W1f-stage / hbuf
    __shared__ __align__(16) float s1s[N_];
    __shared__ __align__(16) float s2s[N_];
    __shared__ __align__(16) float e2s[N_];
    __shared__ __align__(16) float f2s[N_];
    ushort* whf = (ushort*)smem;

    const int bid = blockIdx.x;
    const int b = bid & 15;           // same-b blocks share an XCD (bid%8 = b%8)
    const int hh = bid >> 4;
    const int h = hh >> 1;
    const int half = hh & 1;

    const int tid = threadIdx.x;
    const int lane = tid & 63;
    const int w = tid >> 6;       // 0..7
    const int lg = lane >> 4;
    const int ll = lane & 15;

    // ================= Phase A: Wh(768x64) + s1/s2 =================
    if constexpr (KT == 16) {
        const ushort* src = Bfrag + h * 16 * 2048;   // 64KB W1f[h]
#pragma unroll
        for (int r = 0; r < 8; ++r)
            gload_lds16(src + r * 4096 + tid * 8, (char*)smem + r * 8192 + w * 1024);
        __syncthreads();
    }

    f32x4 acc[6][4];
    f32x4 accs[6];
#pragma unroll
    for (int i = 0; i < 6; ++i) {
        accs[i] = (f32x4){0.f, 0.f, 0.f, 0.f};
#pragma unroll
        for (int nt = 0; nt < 4; ++nt) acc[i][nt] = (f32x4){0.f, 0.f, 0.f, 0.f};
    }

    const int rt_base = b * 48 + w * 6;
    auto loadA6 = [&](bf16x8* dst, int kt) {
#pragma unroll
        for (int i = 0; i < 6; ++i)
            dst[i] = *(const bf16x8*)&Afrag[((rt_base + i) * KT + kt) * 512 + lane * 8];
    };
    auto loadB4 = [&](bf16x8* dst, int kt) {
        if constexpr (KT == 16) {
#pragma unroll
            for (int nt = 0; nt < 4; ++nt)
                dst[nt] = *(const bf16x8*)&whf[kt * 2048 + nt * 512 + lane * 8];
        } else {
#pragma unroll
            for (int nt = 0; nt < 4; ++nt)
                dst[nt] = *(const bf16x8*)&Bfrag[((h * 2 + kt) * 4 + nt) * 512 + lane * 8];
        }
    };
    auto stepA = [&](const bf16x8* afr, const bf16x8* bfr, bf16x8 ufr) {
#pragma unroll
        for (int i = 0; i < 6; ++i) {
#pragma unroll
            for (int nt = 0; nt < 4; ++nt)
                acc[i][nt] = __builtin_amdgcn_mfma_f32_16x16x32_bf16(afr[i], bfr[nt], acc[i][nt], 0, 0, 0);
            accs[i] = __builtin_amdgcn_mfma_f32_16x16x32_bf16(afr[i], ufr, accs[i], 0, 0, 0);
        }
    };

    {
        bf16x8 aA[6], aB[6];
        loadA6(aA, 0);
        for (int kt = 0; kt < KT; kt += 2) {
            loadA6(aB, kt + 1);                 // KT even: kt+1 < KT always
            bf16x8 bfr[4];
            loadB4(bfr, kt);
            bf16x8 ufr = *(const bf16x8*)&uF[(h * KT + kt) * 512 + lane * 8];
            stepA(aA, bfr, ufr);
            if (kt + 2 < KT) loadA6(aA, kt + 2);
            loadB4(bfr, kt + 1);
            ufr = *(const bf16x8*)&uF[(h * KT + kt + 1) * 512 + lane * 8];
            stepA(aB, bfr, ufr);
        }
    }
    if constexpr (KT == 16) __syncthreads();  // staged-B reads done before overwrite

    // Wh fragments -> LDS (j-packed b64), s1/s2 -> LDS (verified round 8)
#pragma unroll
    for (int i = 0; i < 6; ++i) {
        const int rt = w * 6 + i;
        const int lp = ((rt * 2 + (lg >> 1)) & 3) * 16 + ll;
        const int j0 = 4 * (lg & 1);
#pragma unroll
        for (int nt = 0; nt < 4; ++nt) {
            bf16x4 pk;
#pragma unroll
            for (int reg = 0; reg < 4; ++reg) pk[reg] = f2bf(acc[i][nt][reg]);
            *(bf16x4*)&whf[(((rt >> 1) * 4 + nt) * 64 + lp) * 8 + j0] = pk;
        }
#pragma unroll
        for (int reg = 0; reg < 4; ++reg) {
            const int row = rt * 16 + lg * 4 + reg;
            if (ll == 0) s1s[row] = accs[i][reg];
            else if (ll == 1) s2s[row] = accs[i][reg];
        }
    }
    __syncthreads();

    // ---- factor arrays: e2 = 2^t2, f2 = 2^{0.2 t2}; per-thread e1/f1 ----
    for (int i = tid; i < N_; i += 512) {
        float t2 = s2s[i];
        e2s[i] = exp2f(t2);
        f2s[i] = exp2f(0.2f * t2);
    }
    const int qbase = half * 384 + w * 48;
    float e1v[3], f1v[3];
#pragma unroll
    for (int mt = 0; mt < 3; ++mt) {
        float t1 = s1s[qbase + mt * 16 + ll];
        e1v[mt] = exp2f(t1);
        f1v[mt] = exp2f(0.2f * t1);
    }
    __syncthreads();

    // ================= Phase B: attention =================
    f32x4 pacc[3][4];
    f32x4 dacc[3];
#pragma unroll
    for (int mt = 0; mt < 3; ++mt) {
        dacc[mt] = (f32x4){0.f, 0.f, 0.f, 0.f};
#pragma unroll
        for (int nt = 0; nt < 4; ++nt) pacc[mt][nt] = (f32x4){0.f, 0.f, 0.f, 0.f};
    }
    bf16x8 onesB;
#pragma unroll
    for (int j = 0; j < 8; ++j) onesB[j] = (ll == 0) ? (short)0x3F80 : (short)0;

    auto loadP = [&](bf16x8* bq, float* ee, float* ff, int kt) {
#pragma unroll
        for (int nt = 0; nt < 4; ++nt)
            bq[nt] = *(const bf16x8*)&whf[kt * 2048 + nt * 512 + lane * 8];
        float4 t0 = *(const float4*)&e2s[kt * 32 + lg * 8];
        float4 t1 = *(const float4*)&e2s[kt * 32 + lg * 8 + 4];
        float4 t2 = *(const float4*)&f2s[kt * 32 + lg * 8];
        float4 t3 = *(const float4*)&f2s[kt * 32 + lg * 8 + 4];
        ee[0] = t0.x; ee[1] = t0.y; ee[2] = t0.z; ee[3] = t0.w;
        ee[4] = t1.x; ee[5] = t1.y; ee[6] = t1.z; ee[7] = t1.w;
        ff[0] = t2.x; ff[1] = t2.y; ff[2] = t2.z; ff[3] = t2.w;
        ff[4] = t3.x; ff[5] = t3.y; ff[6] = t3.z; ff[7] = t3.w;
    };
    auto stepB = [&](const bf16x8* bq, const float* ee, const float* ff) {
#pragma unroll
        for (int mt = 0; mt < 3; ++mt) {
            bf16x8 af;
#pragma unroll
            for (int j = 0; j < 8; ++j)
                af[j] = f2bf(fmaxf(e1v[mt] * ee[j], f1v[mt] * ff[j]));
            dacc[mt] = __builtin_amdgcn_mfma_f32_16x16x32_bf16(af, onesB, dacc[mt], 0, 0, 0);
#pragma unroll
            for (int nt = 0; nt < 4; ++nt)
                pacc[mt][nt] = __builtin_amdgcn_mfma_f32_16x16x32_bf16(af, bq[nt], pacc[mt][nt], 0, 0, 0);
        }
    };

    {
        bf16x8 bqA[4], bqB[4];
        float eA[8], fA[8], eB[8], fB[8];
        loadP(bqA, eA, fA, 0);
        for (int kt = 0; kt < 24; kt += 2) {
            loadP(bqB, eB, fB, kt + 1);
            stepB(bqA, eA, fA);
            if (kt + 2 < 24) loadP(bqA, eA, fA, kt + 2);
            stepB(bqB, eB, fB);
        }
    }
    __syncthreads();   // all whf reads done; reuse smem as hbuf (384 rows x 128B)

    char* hb8 = smem;
#pragma unroll
    for (int mt = 0; mt < 3; ++mt) {
#pragma unroll
        for (int reg = 0; reg < 4; ++reg) {
            const int rl = w * 48 + mt * 16 + lg * 4 + reg;   // 0..383 local row
            const float dv = __shfl(dacc[mt][reg], lane & 0x30);  // rowsum at ll==0
            const float inv = 1.0f / dv;
            const int swz = (rl & 7) << 4;
#pragma unroll
            for (int nt = 0; nt < 4; ++nt) {
                int c = nt * 16 + ll;
                *(ushort*)(hb8 + rl * 128 + ((c * 2) ^ swz)) =
                    (ushort)f2bf(pacc[mt][nt][reg] * inv);
            }
        }
    }
    __syncthreads();

    // fragment read + coalesced global store (verified epilogue)
#pragma unroll
    for (int rt2 = 0; rt2 < 3; ++rt2) {
#pragma unroll
        for (int kc = 0; kc < 2; ++kc) {
            const int rtl = w * 3 + rt2;
            const int row = rtl * 16 + ll;
            bf16x8 v = *(const bf16x8*)(hb8 + row * 128 +
                                        ((kc * 64 + lg * 16) ^ ((row & 7) << 4)));
            const int rtg = b * 48 + half * 24 + rtl;
            *(bf16x8*)&hpA[((rtg * 16) + (h * 2 + kc)) * 512 + lane * 8] = v;
        }
    }
}

// -------- output projection on MFMA (verified round 5) --------
__global__ __launch_bounds__(256) void k_projm(const ushort* __restrict__ hpA,
                                               const ushort* __restrict__ pwf,
                                               const float* __restrict__ bias,
                                               float* __restrict__ out) {
    const int blk = blockIdx.x;          // 384 blocks, 32 rows each
    const int lane = threadIdx.x & 63;
    const int w = threadIdx.x >> 6;
    const int wrow = w >> 1, wcol = w & 1;
    const int lg = lane >> 4;
    const int ll = lane & 15;

    f32x4 acc[4];
#pragma unroll
    for (int nt = 0; nt < 4; ++nt) acc[nt] = (f32x4){0.f, 0.f, 0.f, 0.f};

    const int rt = blk * 2 + wrow;
    for (int kt = 0; kt < 16; ++kt) {
        bf16x8 afr = *(const bf16x8*)&hpA[((rt * 16) + kt) * 512 + lane * 8];
        bf16x8 bfr[4];
#pragma unroll
        for (int nt = 0; nt < 4; ++nt)
            bfr[nt] = *(const bf16x8*)&pwf[((kt * 8) + wcol * 4 + nt) * 512 + lane * 8];
#pragma unroll
        for (int nt = 0; nt < 4; ++nt)
            acc[nt] = __builtin_amdgcn_mfma_f32_16x16x32_bf16(afr, bfr[nt], acc[nt], 0, 0, 0);
    }

#pragma unroll
    for (int reg = 0; reg < 4; ++reg) {
        const int row = blk * 32 + wrow * 16 + lg * 4 + reg;
#pragma unroll
        for (int nt = 0; nt < 4; ++nt) {
            const int col = wcol * 64 + nt * 16 + ll;
            out[row * EMB_ + col] = acc[nt][reg] + bias[col];
        }
    }
}

extern "C" void kernel_launch(void* const* d_in, const int* in_sizes, int n_in,
                              void* d_out, int out_size, void* d_ws, size_t ws_size,
                              hipStream_t stream) {
    const float* x    = (const float*)d_in[0];
    const float* ip_w = (const float*)d_in[1];
    const float* ip_b = (const float*)d_in[2];
    const float* gw0  = (const float*)d_in[3];
    const float* ga0  = (const float*)d_in[4];
    const float* gw1  = (const float*)d_in[5];
    const float* ga1  = (const float*)d_in[6];
    const float* pw   = (const float*)d_in[7];
    const float* pb   = (const float*)d_in[8];
    float* out = (float*)d_out;

    ushort* h0A  = (ushort*)d_ws;        // 786432 us
    ushort* hpA0 = h0A + 786432;         // 6291456 us
    ushort* hpA1 = hpA0 + 6291456;       // 6291456 us
    ushort* W1f  = hpA1 + 6291456;       // 262144 us
    ushort* pwf  = W1f + 262144;         // 65536 us
    ushort* W0f  = pwf + 65536;          // 32768 us
    ushort* u1F  = W0f + 32768;          // 65536 us
    ushort* u0F  = u1F + 65536;          // 8192 us

    k_prep<<<704, 256, 0, stream>>>(x, ip_w, ip_b, gw1, pw, gw0, ga1, ga0,
                                    h0A, W1f, pwf, W0f, u1F, u0F);
    k_gat<2><<<256, 512, 0, stream>>>(h0A, W0f, u0F, hpA0);
    k_gat<16><<<256, 512, 0, stream>>>(hpA0, W1f, u1F, hpA1);
    k_projm<<<(B_ * N_) / 32, 256, 0, stream>>>(hpA1, pwf, pb, out);
}

// Round 10
// 145.715 us; speedup vs baseline: 1.2845x; 1.0059x over previous
//
#include <hip/hip_runtime.h>
#include <hip/hip_bf16.h>

// GAT encoder: B=16, N=768, IN=16, HID=64, HEADS=8, EMB=128, 2 GAT layers.
// Round 10: k_gat re-partitioned 8 -> 12 waves (768 thr, 3 waves/SIMD) for
// +50% TLP at same LDS. Phase A: 4 rt/wave; phase B: 2 mt (32 query rows)/wave;
// epilogue 2 rt-tiles/wave; W1f staged in 1KB wave-chunks. Math/layouts are
// round-9-verified and unchanged. k_prep / k_projm identical to round 9.
//
// ws: h0A us[786432] | hpA0 us[6291456] | hpA1 us[6291456] | W1f us[262144]
//     | pwf us[65536] | W0f us[32768] | u1F us[65536] | u0F us[8192]

#define B_ 16
#define N_ 768
#define IN_DIM_ 16
#define HID_ 64
#define EMB_ 128
#define NH_ 8
#define LOG2E_ 1.4426950408889634f

typedef __attribute__((ext_vector_type(4))) float f32x4;
typedef __attribute__((ext_vector_type(8))) short bf16x8;
typedef __attribute__((ext_vector_type(4))) short bf16x4;

typedef __attribute__((address_space(1))) const unsigned int gu32;
typedef __attribute__((address_space(3))) unsigned int lu32;

static __device__ __forceinline__ void gload_lds16(const void* g, void* l) {
    __builtin_amdgcn_global_load_lds((gu32*)g, (lu32*)l, 16, 0, 0);
}

static __device__ __forceinline__ short f2bf(float x) {
    __hip_bfloat16 b = __float2bfloat16(x);
    return *reinterpret_cast<short*>(&b);
}

// ---- prep: h0A A-frags + W1f/pwf/W0f B-frags + u1F/u0F u-fragments ----
__global__ __launch_bounds__(256) void k_prep(const float* __restrict__ x,
                                              const float* __restrict__ ipw,
                                              const float* __restrict__ ipb,
                                              const float* __restrict__ w1,
                                              const float* __restrict__ pw,
                                              const float* __restrict__ w0,
                                              const float* __restrict__ a1g,
                                              const float* __restrict__ a0g,
                                              ushort* __restrict__ h0A,
                                              ushort* __restrict__ W1f,
                                              ushort* __restrict__ pwf,
                                              ushort* __restrict__ W0f,
                                              ushort* __restrict__ u1F,
                                              ushort* __restrict__ u0F) {
    const int bid = blockIdx.x;
    const int tid = threadIdx.x;
    if (bid < 384) {
        const int t = bid * 256 + tid;  // < 98304
        const int lane = t & 63;
        const int kt = (t >> 6) & 1;
        const int rtg = t >> 7;
        const int row = rtg * 16 + (lane & 15);
        const int k0 = kt * 32 + (lane >> 4) * 8;
        const float* xr = x + row * IN_DIM_;
        float xv[IN_DIM_];
#pragma unroll
        for (int f = 0; f < IN_DIM_; ++f) xv[f] = xr[f];
        bf16x8 v;
#pragma unroll
        for (int j = 0; j < 8; ++j) {
            float acc = ipb[k0 + j];
#pragma unroll
            for (int f = 0; f < IN_DIM_; ++f) acc = fmaf(xv[f], ipw[f * HID_ + k0 + j], acc);
            v[j] = f2bf(acc);
        }
        *(bf16x8*)&h0A[t * 8] = v;
        return;
    }
    if (bid < 560) {
        int t = (bid - 384) * 256 + tid;  // < 45056
        if (t < 32768) {
            int lane = t & 63, nt = (t >> 6) & 3, kt = (t >> 8) & 15, h = t >> 12;
            int k0 = kt * 32 + (lane >> 4) * 8;
            int col = nt * 16 + (lane & 15);
            const float* src = w1 + (h * 512 + k0) * 64 + col;
            bf16x8 v;
#pragma unroll
            for (int j = 0; j < 8; ++j) v[j] = f2bf(src[j * 64]);
            *(bf16x8*)&W1f[t * 8] = v;
        } else if (t < 40960) {
            int u = t - 32768;
            int lane = u & 63, nt = (u >> 6) & 7, kt = u >> 9;
            int k0 = kt * 32 + (lane >> 4) * 8;
            int col = nt * 16 + (lane & 15);
            const float* src = pw + k0 * 128 + col;
            bf16x8 v;
#pragma unroll
            for (int j = 0; j < 8; ++j) v[j] = f2bf(src[j * 128]);
            *(bf16x8*)&pwf[u * 8] = v;
        } else {
            int u = t - 40960;
            int lane = u & 63, nt = (u >> 6) & 3, kt = (u >> 8) & 1, h = u >> 9;
            int k0 = kt * 32 + (lane >> 4) * 8;
            int col = nt * 16 + (lane & 15);
            const float* src = w0 + (h * 64 + k0) * 64 + col;
            bf16x8 v;
#pragma unroll
            for (int j = 0; j < 8; ++j) v[j] = f2bf(src[j * 64]);
            *(bf16x8*)&W0f[u * 8] = v;
        }
        return;
    }
    // u-fragment blocks: one block per (layer,h,kt) -> zero + fill ll<2 lanes
    int ub = bid - 560;  // < 144
    const float* W;
    const float* A;
    ushort* dst;
    if (ub < 128) {
        int h = ub >> 4, kt = ub & 15;
        W = w1 + (h * 512 + kt * 32) * 64;
        A = a1g + h * 128;
        dst = u1F + (h * 16 + kt) * 512;
    } else {
        int v2 = ub - 128;
        int h = v2 >> 1, kt = v2 & 1;
        W = w0 + (h * 64 + kt * 32) * 64;
        A = a0g + h * 128;
        dst = u0F + (h * 2 + kt) * 512;
    }
    ((unsigned int*)dst)[tid] = 0u;   // zero 512 ushorts
    __syncthreads();
    const int sel = tid >> 7, kl = (tid >> 2) & 31, og4 = tid & 3;
    const float* Wr = W + kl * 64 + og4 * 16;
    const float* Ar = A + sel * 64 + og4 * 16;
    float r = 0.f;
#pragma unroll
    for (int q = 0; q < 4; ++q) {
        float4 wv = *(const float4*)&Wr[q * 4];
        float4 av = *(const float4*)&Ar[q * 4];
        r += wv.x * av.x + wv.y * av.y + wv.z * av.z + wv.w * av.w;
    }
    r += __shfl_xor(r, 1);
    r += __shfl_xor(r, 2);
    if (og4 == 0)
        dst[((kl >> 3) * 16 + sel) * 8 + (kl & 7)] = (ushort)f2bf(r * LOG2E_);
}

// ---- fused GAT layer: block (b,h,half), 12 waves -> Wh in LDS -> attention ----
template <int KT>
__global__ __launch_bounds__(768, 3) void k_gat(const ushort* __restrict__ Afrag,
                                                const ushort* __restrict__ Bfrag,
                                                const ushort* __restrict__ uF,
                                                ushort* __restrict__ hpA) {
    __shared__ __align__(16) char smem[98304];  // Whf frags; aliases W1f-stage / hbuf
    __shared__ __align__(16) float s1s[N_];
    __shared__ __align__(16) float s2s[N_];
    __shared__ __align__(16) float e2s[N_];
    __shared__ __align__(16) float f2s[N_];
    ushort* whf = (ushort*)smem;

    const int bid = blockIdx.x;
    const int b = bid & 15;           // same-b blocks share an XCD (bid%8 = b%8)
    const int hh = bid >> 4;
    const int h = hh >> 1;
    const int half = hh & 1;

    const int tid = threadIdx.x;
    const int lane = tid & 63;
    const int w = tid >> 6;       // 0..11
    const int lg = lane >> 4;
    const int ll = lane & 15;

    // ================= Phase A: Wh(768x64) + s1/s2 =================
    if constexpr (KT == 16) {
        const ushort* src = Bfrag + h * 16 * 2048;   // 64KB W1f[h] in 1KB wave-chunks
        for (int c = w; c < 64; c += 12)
            gload_lds16(src + c * 512 + lane * 8, (char*)smem + c * 1024);
        __syncthreads();
    }

    f32x4 acc[4][4];
    f32x4 accs[4];
#pragma unroll
    for (int i = 0; i < 4; ++i) {
        accs[i] = (f32x4){0.f, 0.f, 0.f, 0.f};
#pragma unroll
        for (int nt = 0; nt < 4; ++nt) acc[i][nt] = (f32x4){0.f, 0.f, 0.f, 0.f};
    }

    const int rt_base = b * 48 + w * 4;
    auto loadA4 = [&](bf16x8* dst, int kt) {
#pragma unroll
        for (int i = 0; i < 4; ++i)
            dst[i] = *(const bf16x8*)&Afrag[((rt_base + i) * KT + kt) * 512 + lane * 8];
    };
    auto loadB4 = [&](bf16x8* dst, int kt) {
        if constexpr (KT == 16) {
#pragma unroll
            for (int nt = 0; nt < 4; ++nt)
                dst[nt] = *(const bf16x8*)&whf[kt * 2048 + nt * 512 + lane * 8];
        } else {
#pragma unroll
            for (int nt = 0; nt < 4; ++nt)
                dst[nt] = *(const bf16x8*)&Bfrag[((h * 2 + kt) * 4 + nt) * 512 + lane * 8];
        }
    };
    auto stepA = [&](const bf16x8* afr, const bf16x8* bfr, bf16x8 ufr) {
#pragma unroll
        for (int i = 0; i < 4; ++i) {
#pragma unroll
            for (int nt = 0; nt < 4; ++nt)
                acc[i][nt] = __builtin_amdgcn_mfma_f32_16x16x32_bf16(afr[i], bfr[nt], acc[i][nt], 0, 0, 0);
            accs[i] = __builtin_amdgcn_mfma_f32_16x16x32_bf16(afr[i], ufr, accs[i], 0, 0, 0);
        }
    };

    {
        bf16x8 aA[4], aB[4];
        loadA4(aA, 0);
        for (int kt = 0; kt < KT; kt += 2) {
            loadA4(aB, kt + 1);                 // KT even: kt+1 < KT always
            bf16x8 bfr[4];
            loadB4(bfr, kt);
            bf16x8 ufr = *(const bf16x8*)&uF[(h * KT + kt) * 512 + lane * 8];
            stepA(aA, bfr, ufr);
            if (kt + 2 < KT) loadA4(aA, kt + 2);
            loadB4(bfr, kt + 1);
            ufr = *(const bf16x8*)&uF[(h * KT + kt + 1) * 512 + lane * 8];
            stepA(aB, bfr, ufr);
        }
    }
    if constexpr (KT == 16) __syncthreads();  // staged-B reads done before overwrite

    // Wh fragments -> LDS (j-packed b64), s1/s2 -> LDS (verified layout)
#pragma unroll
    for (int i = 0; i < 4; ++i) {
        const int rt = w * 4 + i;
        const int lp = ((rt * 2 + (lg >> 1)) & 3) * 16 + ll;
        const int j0 = 4 * (lg & 1);
#pragma unroll
        for (int nt = 0; nt < 4; ++nt) {
            bf16x4 pk;
#pragma unroll
            for (int reg = 0; reg < 4; ++reg) pk[reg] = f2bf(acc[i][nt][reg]);
            *(bf16x4*)&whf[(((rt >> 1) * 4 + nt) * 64 + lp) * 8 + j0] = pk;
        }
#pragma unroll
        for (int reg = 0; reg < 4; ++reg) {
            const int row = rt * 16 + lg * 4 + reg;
            if (ll == 0) s1s[row] = accs[i][reg];
            else if (ll == 1) s2s[row] = accs[i][reg];
        }
    }
    __syncthreads();

    // ---- factor arrays: e2 = 2^t2, f2 = 2^{0.2 t2}; per-thread e1/f1 ----
    for (int i = tid; i < N_; i += 768) {
        float t2 = s2s[i];
        e2s[i] = exp2f(t2);
        f2s[i] = exp2f(0.2f * t2);
    }
    const int qbase = half * 384 + w * 32;
    float e1v[2], f1v[2];
#pragma unroll
    for (int mt = 0; mt < 2; ++mt) {
        float t1 = s1s[qbase + mt * 16 + ll];
        e1v[mt] = exp2f(t1);
        f1v[mt] = exp2f(0.2f * t1);
    }
    __syncthreads();

    // ================= Phase B: attention (2 mt per wave) =================
    f32x4 pacc[2][4];
    f32x4 dacc[2];
#pragma unroll
    for (int mt = 0; mt < 2; ++mt) {
        dacc[mt] = (f32x4){0.f, 0.f, 0.f, 0.f};
#pragma unroll
        for (int nt = 0; nt < 4; ++nt) pacc[mt][nt] = (f32x4){0.f, 0.f, 0.f, 0.f};
    }
    bf16x8 onesB;
#pragma unroll
    for (int j = 0; j < 8; ++j) onesB[j] = (ll == 0) ? (short)0x3F80 : (short)0;

    auto loadP = [&](bf16x8* bq, float* ee, float* ff, int kt) {
#pragma unroll
        for (int nt = 0; nt < 4; ++nt)
            bq[nt] = *(const bf16x8*)&whf[kt * 2048 + nt * 512 + lane * 8];
        float4 t0 = *(const float4*)&e2s[kt * 32 + lg * 8];
        float4 t1 = *(const float4*)&e2s[kt * 32 + lg * 8 + 4];
        float4 t2 = *(const float4*)&f2s[kt * 32 + lg * 8];
        float4 t3 = *(const float4*)&f2s[kt * 32 + lg * 8 + 4];
        ee[0] = t0.x; ee[1] = t0.y; ee[2] = t0.z; ee[3] = t0.w;
        ee[4] = t1.x; ee[5] = t1.y; ee[6] = t1.z; ee[7] = t1.w;
        ff[0] = t2.x; ff[1] = t2.y; ff[2] = t2.z; ff[3] = t2.w;
        ff[4] = t3.x; ff[5] = t3.y; ff[6] = t3.z; ff[7] = t3.w;
    };
    auto stepB = [&](const bf16x8* bq, const float* ee, const float* ff) {
#pragma unroll
        for (int mt = 0; mt < 2; ++mt) {
            bf16x8 af;
#pragma unroll
            for (int j = 0; j < 8; ++j)
                af[j] = f2bf(fmaxf(e1v[mt] * ee[j], f1v[mt] * ff[j]));
            dacc[mt] = __builtin_amdgcn_mfma_f32_16x16x32_bf16(af, onesB, dacc[mt], 0, 0, 0);
#pragma unroll
            for (int nt = 0; nt < 4; ++nt)
                pacc[mt][nt] = __builtin_amdgcn_mfma_f32_16x16x32_bf16(af, bq[nt], pacc[mt][nt], 0, 0, 0);
        }
    };

    {
        bf16x8 bqA[4], bqB[4];
        float eA[8], fA[8], eB[8], fB[8];
        loadP(bqA, eA, fA, 0);
        for (int kt = 0; kt < 24; kt += 2) {
            loadP(bqB, eB, fB, kt + 1);
            stepB(bqA, eA, fA);
            if (kt + 2 < 24) loadP(bqA, eA, fA, kt + 2);
            stepB(bqB, eB, fB);
        }
    }
    __syncthreads();   // all whf reads done; reuse smem as hbuf (384 rows x 128B)

    char* hb8 = smem;
#pragma unroll
    for (int mt = 0; mt < 2; ++mt) {
#pragma unroll
        for (int reg = 0; reg < 4; ++reg) {
            const int rl = w * 32 + mt * 16 + lg * 4 + reg;   // 0..383 local row
            const float dv = __shfl(dacc[mt][reg], lane & 0x30);  // rowsum at ll==0
            const float inv = 1.0f / dv;
            const int swz = (rl & 7) << 4;
#pragma unroll
            for (int nt = 0; nt < 4; ++nt) {
                int c = nt * 16 + ll;
                *(ushort*)(hb8 + rl * 128 + ((c * 2) ^ swz)) =
                    (ushort)f2bf(pacc[mt][nt][reg] * inv);
            }
        }
    }
    __syncthreads();

    // fragment read + coalesced global store (verified epilogue, 2 rt-tiles/wave)
#pragma unroll
    for (int rt2 = 0; rt2 < 2; ++rt2) {
#pragma unroll
        for (int kc = 0; kc < 2; ++kc) {
            const int rtl = w * 2 + rt2;
            const int row = rtl * 16 + ll;
            bf16x8 v = *(const bf16x8*)(hb8 + row * 128 +
                                        ((kc * 64 + lg * 16) ^ ((row & 7) << 4)));
            const int rtg = b * 48 + half * 24 + rtl;
            *(bf16x8*)&hpA[((rtg * 16) + (h * 2 + kc)) * 512 + lane * 8] = v;
        }
    }
}

// -------- output projection on MFMA (verified round 5) --------
__global__ __launch_bounds__(256) void k_projm(const ushort* __restrict__ hpA,
                                               const ushort* __restrict__ pwf,
                                               const float* __restrict__ bias,
                                               float* __restrict__ out) {
    const int blk = blockIdx.x;          // 384 blocks, 32 rows each
    const int lane = threadIdx.x & 63;
    const int w = threadIdx.x >> 6;
    const int wrow = w >> 1, wcol = w & 1;
    const int lg = lane >> 4;
    const int ll = lane & 15;

    f32x4 acc[4];
#pragma unroll
    for (int nt = 0; nt < 4; ++nt) acc[nt] = (f32x4){0.f, 0.f, 0.f, 0.f};

    const int rt = blk * 2 + wrow;
    for (int kt = 0; kt < 16; ++kt) {
        bf16x8 afr = *(const bf16x8*)&hpA[((rt * 16) + kt) * 512 + lane * 8];
        bf16x8 bfr[4];
#pragma unroll
        for (int nt = 0; nt < 4; ++nt)
            bfr[nt] = *(const bf16x8*)&pwf[((kt * 8) + wcol * 4 + nt) * 512 + lane * 8];
#pragma unroll
        for (int nt = 0; nt < 4; ++nt)
            acc[nt] = __builtin_amdgcn_mfma_f32_16x16x32_bf16(afr, bfr[nt], acc[nt], 0, 0, 0);
    }

#pragma unroll
    for (int reg = 0; reg < 4; ++reg) {
        const int row = blk * 32 + wrow * 16 + lg * 4 + reg;
#pragma unroll
        for (int nt = 0; nt < 4; ++nt) {
            const int col = wcol * 64 + nt * 16 + ll;
            out[row * EMB_ + col] = acc[nt][reg] + bias[col];
        }
    }
}

extern "C" void kernel_launch(void* const* d_in, const int* in_sizes, int n_in,
                              void* d_out, int out_size, void* d_ws, size_t ws_size,
                              hipStream_t stream) {
    const float* x    = (const float*)d_in[0];
    const float* ip_w = (const float*)d_in[1];
    const float* ip_b = (const float*)d_in[2];
    const float* gw0  = (const float*)d_in[3];
    const float* ga0  = (const float*)d_in[4];
    const float* gw1  = (const float*)d_in[5];
    const float* ga1  = (const float*)d_in[6];
    const float* pw   = (const float*)d_in[7];
    const float* pb   = (const float*)d_in[8];
    float* out = (float*)d_out;

    ushort* h0A  = (ushort*)d_ws;        // 786432 us
    ushort* hpA0 = h0A + 786432;         // 6291456 us
    ushort* hpA1 = hpA0 + 6291456;       // 6291456 us
    ushort* W1f  = hpA1 + 6291456;       // 262144 us
    ushort* pwf  = W1f + 262144;         // 65536 us
    ushort* W0f  = pwf + 65536;          // 32768 us
    ushort* u1F  = W0f + 32768;          // 65536 us
    ushort* u0F  = u1F + 65536;          // 8192 us

    k_prep<<<704, 256, 0, stream>>>(x, ip_w, ip_b, gw1, pw, gw0, ga1, ga0,
                                    h0A, W1f, pwf, W0f, u1F, u0F);
    k_gat<2><<<256, 768, 0, stream>>>(h0A, W0f, u0F, hpA0);
    k_gat<16><<<256, 768, 0, stream>>>(hpA0, W1f, u1F, hpA1);
    k_projm<<<(B_ * N_) / 32, 256, 0, stream>>>(hpA1, pwf, pb, out);
}